// Round 1
// baseline (93.974 us; speedup 1.0000x reference)
//
#include <hip/hip_runtime.h>

#define EPSF 1e-8f
#define R2C 0.0025f   // 0.05^2

// ---------------- ws float layout ----------------
// scal[0..2]  : sum of head-masked points (x,y,z)
// scal[3]     : n_head
// scal[4]     : pv  (pred count)
// scal[5]     : gv  (gt count)
// scal[6]     : nb  (boundary count)
// scal[7..12] : cov sums xx,xy,xz,yy,yz,zz
// scal[13]    : sum d*hf
// scal[14]    : sum hf*d^2
// scal[15]    : max d over head mask (float bits, atomicMax as int)
// scal[16]    : sum_var (surface)
// scal[17]    : ni
// scal[18..21]: mask-layout violation counters (0 => int32 layout)
// then: cnt[n], sx[n], sx2[n], pos4[n] (float4), xv[n]

__device__ inline int read_mask(const void* p, int i, int isInt) {
    if (isInt) return ((const int*)p)[i] != 0;
    return ((const unsigned char*)p)[i] != 0;
}

__device__ inline float wave_sum(float v) {
    #pragma unroll
    for (int o = 32; o > 0; o >>= 1) v += __shfl_down(v, o, 64);
    return v;
}
__device__ inline float wave_max(float v) {
    #pragma unroll
    for (int o = 32; o > 0; o >>= 1) v = fmaxf(v, __shfl_down(v, o, 64));
    return v;
}

// Detect whether each mask buffer is int32 (upper 3 bytes of every word zero)
// or byte-sized. Only reads n bytes, safe for both layouts.
__global__ void detect_kernel(const void* m0, const void* m1, const void* m2,
                              const void* m3, float* scal, int n) {
    const unsigned char* ms[4] = {(const unsigned char*)m0, (const unsigned char*)m1,
                                  (const unsigned char*)m2, (const unsigned char*)m3};
    int words = n / 4;
    for (int m = 0; m < 4; ++m) {
        const unsigned char* u = ms[m];
        int bad = 0;
        for (int k = threadIdx.x; k < words; k += blockDim.x)
            bad |= u[4*k+1] | u[4*k+2] | u[4*k+3];
        if (bad) atomicAdd(&scal[18 + m], 1.0f);
    }
}

__global__ void passA(const float* __restrict__ pts, const float* __restrict__ segp,
                      const void* bm, const void* hm, const void* pm, const void* gm,
                      float* ws, int n) {
    float* scal = ws;
    int i = blockIdx.x * blockDim.x + threadIdx.x;
    if (i >= n) return;
    int bInt = (scal[18] == 0.0f), hInt = (scal[19] == 0.0f);
    int pInt = (scal[20] == 0.0f), gInt = (scal[21] == 0.0f);

    float x = pts[3*i], y = pts[3*i+1], z = pts[3*i+2];
    float xv = segp[3*i+2];
    int b = read_mask(bm, i, bInt);
    int h = read_mask(hm, i, hInt);
    int p = read_mask(pm, i, pInt);
    int g = read_mask(gm, i, gInt);
    float sq = x*x + y*y + z*z;

    float4* pos4 = (float4*)(ws + 64 + 3*n);
    float*  xvar = ws + 64 + 7*n;
    // non-boundary j: push sq by +1000 so d2 >= ~994 >> R2 always (exact masking)
    pos4[i] = make_float4(x, y, z, b ? sq : sq + 1000.0f);
    xvar[i] = xv;

    float hf = h ? 1.0f : 0.0f;
    float vals[7] = { hf*x, hf*y, hf*z, hf, (float)p, (float)g, (float)b };
    #pragma unroll
    for (int k = 0; k < 7; ++k) {
        float s = wave_sum(vals[k]);
        if ((threadIdx.x & 63) == 0) atomicAdd(&scal[k], s);
    }
}

__global__ void passB(const float* __restrict__ pts, const void* hm, float* ws, int n) {
    float* scal = ws;
    int i = blockIdx.x * blockDim.x + threadIdx.x;
    if (i >= n) return;
    int hInt = (scal[19] == 0.0f);
    float nh = scal[3];
    float cx0 = 0.f, cy0 = 0.f, cz0 = 0.f;
    if (nh > 0.0f) { cx0 = scal[0]/nh; cy0 = scal[1]/nh; cz0 = scal[2]/nh; }

    float x = pts[3*i], y = pts[3*i+1], z = pts[3*i+2];
    int h = read_mask(hm, i, hInt);
    float m = h ? 1.0f : 0.0f;
    float dx = x - cx0, dy = y - cy0, dz = z - cz0;
    float d = sqrtf(dx*dx + dy*dy + dz*dz);

    float vals[8] = { m*dx*dx, m*dx*dy, m*dx*dz, m*dy*dy, m*dy*dz, m*dz*dz,
                      m*d, m*d*d };
    #pragma unroll
    for (int k = 0; k < 8; ++k) {
        float s = wave_sum(vals[k]);
        if ((threadIdx.x & 63) == 0) atomicAdd(&scal[7 + k], s);
    }
    float dm = wave_max(h ? d : 0.0f);
    if ((threadIdx.x & 63) == 0) atomicMax((int*)&scal[15], __float_as_int(dm));
}

// O(N^2) neighborhood accumulation. grid = (n/256, NCHUNK)
__global__ void passC(const float4* __restrict__ pos4, const float* __restrict__ xv,
                      float* __restrict__ cnt, float* __restrict__ sx,
                      float* __restrict__ sx2, int n, int chunk) {
    __shared__ float4 t4[256];
    __shared__ float  tx[256];
    int i = blockIdx.x * blockDim.x + threadIdx.x;
    float4 pi = pos4[i];
    float ci = 0.f, s1 = 0.f, s2 = 0.f;
    int j0 = blockIdx.y * chunk;
    for (int jt = j0; jt < j0 + chunk; jt += 256) {
        __syncthreads();
        t4[threadIdx.x] = pos4[jt + threadIdx.x];
        tx[threadIdx.x] = xv[jt + threadIdx.x];
        __syncthreads();
        #pragma unroll 4
        for (int k = 0; k < 256; ++k) {
            float4 pj = t4[k];
            float d2 = pi.w + pj.w - 2.0f*(pi.x*pj.x + pi.y*pj.y + pi.z*pj.z);
            float v = tx[k];
            bool w = d2 < R2C;
            ci += w ? 1.0f : 0.0f;
            s1 += w ? v   : 0.0f;
            s2 += w ? v*v : 0.0f;
        }
    }
    atomicAdd(&cnt[i], ci);
    atomicAdd(&sx[i],  s1);
    atomicAdd(&sx2[i], s2);
}

__global__ void passD(const void* bm, float* ws, int n) {
    float* scal = ws;
    int i = blockIdx.x * blockDim.x + threadIdx.x;
    if (i >= n) return;
    int bInt = (scal[18] == 0.0f);
    float c  = ws[64 + i];
    float s1 = ws[64 + n + i];
    float s2 = ws[64 + 2*n + i];
    int b = read_mask(bm, i, bInt);
    float safe_n = fmaxf(c, 2.0f);
    float var = (s2 - s1*s1/safe_n) / (safe_n - 1.0f);
    bool inc = (c > 1.0f) && b;
    float sv = wave_sum(inc ? var : 0.0f);
    float nv = wave_sum(inc ? 1.0f : 0.0f);
    if ((threadIdx.x & 63) == 0) {
        atomicAdd(&scal[16], sv);
        atomicAdd(&scal[17], nv);
    }
}

__global__ void passE(const float* scal, float* out) {
    // ---- ellipsoid shape loss ----
    float nh = scal[3];
    float el = 0.0f;
    if (nh >= 10.0f) {
        double n  = (double)nh;
        double axx = scal[7]/n,  axy = scal[8]/n,  axz = scal[9]/n;
        double ayy = scal[10]/n, ayz = scal[11]/n, azz = scal[12]/n;
        double p1 = axy*axy + axz*axz + ayz*ayz;
        double q  = (axx + ayy + azz) / 3.0;
        double p2 = (axx-q)*(axx-q) + (ayy-q)*(ayy-q) + (azz-q)*(azz-q) + 2.0*p1;
        double e0, e1, e2;
        if (p2 < 1e-300) { e0 = e1 = e2 = q; }
        else {
            double p = sqrt(p2 / 6.0);
            double bxx = (axx-q)/p, byy = (ayy-q)/p, bzz = (azz-q)/p;
            double bxy = axy/p, bxz = axz/p, byz = ayz/p;
            double detB = bxx*(byy*bzz - byz*byz) - bxy*(bxy*bzz - byz*bxz)
                        + bxz*(bxy*byz - byy*bxz);
            double r = detB * 0.5;
            r = fmin(1.0, fmax(-1.0, r));
            double phi = acos(r) / 3.0;
            double eig1 = q + 2.0*p*cos(phi);                       // largest
            double eig3 = q + 2.0*p*cos(phi + 2.0943951023931953);  // smallest
            double eig2 = 3.0*q - eig1 - eig3;
            e2 = eig1; e1 = eig2; e0 = eig3;
        }
        double a = e2, b = e1, c = e0;
        double ra = b/(a + (double)EPSF) - 1.0;
        double rc = c/(a + (double)EPSF) - 1.0;
        el = (float)(ra*ra + rc*rc);
    }
    // ---- size consistency ----
    float pv = scal[4], gv = scal[5];
    float diff = pv - gv;
    float vol = diff * diff;
    float rel = fabsf(diff) / (gv > 0.0f ? gv : 1.0f);
    float sc = (gv > 0.0f) ? vol + 0.5f*rel : vol;
    // ---- surface smoothness ----
    float nb = scal[6], sv = scal[16], ni = scal[17];
    float mean_var = sv / fmaxf(ni, 1.0f);
    float ss = ((nb >= 5.0f) && (ni > 0.0f)) ? mean_var : 0.0f;
    // ---- connectivity ----
    float conn = 0.0f;
    if (nh >= 5.0f) {
        float sd = scal[13], sd2 = scal[14];
        float var = (sd2 - sd*sd/nh) / (nh - 1.0f);
        float maxd = scal[15];
        conn = var / (maxd + EPSF);
    }
    out[0] = el + sc + ss + conn;
}

extern "C" void kernel_launch(void* const* d_in, const int* in_sizes, int n_in,
                              void* d_out, int out_size, void* d_ws, size_t ws_size,
                              hipStream_t stream) {
    const float* points = (const float*)d_in[0];
    const float* segp   = (const float*)d_in[1];
    const void*  bmask  = d_in[2];
    const void*  hmask  = d_in[3];
    const void*  pmask  = d_in[4];
    const void*  gmask  = d_in[5];
    float* ws  = (float*)d_ws;
    float* out = (float*)d_out;
    int n = in_sizes[2];            // 8192

    // zero scalars + cnt/sx/sx2 (self-init every call; harness doesn't re-poison)
    hipMemsetAsync(d_ws, 0, (size_t)(64 + 3*n) * sizeof(float), stream);

    detect_kernel<<<1, 256, 0, stream>>>(bmask, hmask, pmask, gmask, ws, n);

    int nb = n / 256;
    passA<<<nb, 256, 0, stream>>>(points, segp, bmask, hmask, pmask, gmask, ws, n);
    passB<<<nb, 256, 0, stream>>>(points, hmask, ws, n);

    const int NCHUNK = 8;
    passC<<<dim3(nb, NCHUNK), 256, 0, stream>>>(
        (const float4*)(ws + 64 + 3*n), ws + 64 + 7*n,
        ws + 64, ws + 64 + n, ws + 64 + 2*n, n, n / NCHUNK);

    passD<<<nb, 256, 0, stream>>>(bmask, ws, n);
    passE<<<1, 1, 0, stream>>>(ws, out);
}

// Round 2
// 54.946 us; speedup vs baseline: 1.7103x; 1.7103x over previous
//
#include <hip/hip_runtime.h>

#define EPSF 1e-8f
#define R2C 0.0025f   // 0.05^2
#define NJ 32         // j-chunks for passC

// ---------------- ws float layout ----------------
// scal[0..2]  : sum of head-masked points (x,y,z)
// scal[3]     : n_head
// scal[4]     : pv, scal[5]: gv, scal[6]: nb
// scal[7..12] : cov sums xx,xy,xz,yy,yz,zz
// scal[13]    : sum d*hf      scal[14]: sum hf*d^2
// scal[15]    : max d (float bits via atomicMax int)
// scal[16]    : sum_var       scal[17]: ni
// scal[18..21]: mask-layout flags (0 => int32 layout)
// ws+64            : pos4[n]  (float4: -2x,-2y,-2z, sq')
// ws+64+4n         : xv2[n]   (float2: v, v^2)
// ws+64+6n (atomic): cnt[n], sx[n], sx2[n]
// ws+64+6n (part)  : cnt_p[NJ][n], sx_p[NJ][n], sx2_p[NJ][n]

__device__ inline int read_mask(const void* p, int i, int isInt) {
    if (isInt) return ((const int*)p)[i] != 0;
    return ((const unsigned char*)p)[i] != 0;
}

__device__ inline float wave_sum(float v) {
    #pragma unroll
    for (int o = 32; o > 0; o >>= 1) v += __shfl_down(v, o, 64);
    return v;
}
__device__ inline float wave_max(float v) {
    #pragma unroll
    for (int o = 32; o > 0; o >>= 1) v = fmaxf(v, __shfl_down(v, o, 64));
    return v;
}

// Zero scal + detect mask layout (int32 vs byte). Single block.
__global__ void detect_kernel(const void* m0, const void* m1, const void* m2,
                              const void* m3, float* scal, int n) {
    if (threadIdx.x < 64) scal[threadIdx.x] = 0.0f;
    __syncthreads();
    const unsigned char* ms[4] = {(const unsigned char*)m0, (const unsigned char*)m1,
                                  (const unsigned char*)m2, (const unsigned char*)m3};
    int words = n / 4;
    for (int m = 0; m < 4; ++m) {
        const unsigned char* u = ms[m];
        int bad = 0;
        for (int k = threadIdx.x; k < words; k += blockDim.x)
            bad |= u[4*k+1] | u[4*k+2] | u[4*k+3];
        if (bad) atomicAdd(&scal[18 + m], 1.0f);
    }
}

__global__ void passA(const float* __restrict__ pts, const float* __restrict__ segp,
                      const void* bm, const void* hm, const void* pm, const void* gm,
                      float* ws, int n) {
    float* scal = ws;
    int i = blockIdx.x * blockDim.x + threadIdx.x;
    if (i >= n) return;
    int bInt = (scal[18] == 0.0f), hInt = (scal[19] == 0.0f);
    int pInt = (scal[20] == 0.0f), gInt = (scal[21] == 0.0f);

    float x = pts[3*i], y = pts[3*i+1], z = pts[3*i+2];
    float v = segp[3*i+2];
    int b = read_mask(bm, i, bInt);
    int h = read_mask(hm, i, hInt);
    int p = read_mask(pm, i, pInt);
    int g = read_mask(gm, i, gInt);
    float sq = x*x + y*y + z*z;

    float4* pos4 = (float4*)(ws + 64);
    float2* xv2  = (float2*)(ws + 64 + 4*n);
    // non-boundary: push sq by +1000 so d2 >= ~994 >> R2 always (exact masking)
    pos4[i] = make_float4(-2.0f*x, -2.0f*y, -2.0f*z, b ? sq : sq + 1000.0f);
    xv2[i]  = make_float2(v, v*v);

    // zero accumulator region (used only in atomic path; harmless otherwise)
    float* acc = ws + 64 + 6*n;
    acc[i] = 0.0f; acc[n+i] = 0.0f; acc[2*n+i] = 0.0f;

    float hf = h ? 1.0f : 0.0f;
    float vals[7] = { hf*x, hf*y, hf*z, hf, (float)p, (float)g, (float)b };
    #pragma unroll
    for (int k = 0; k < 7; ++k) {
        float s = wave_sum(vals[k]);
        if ((threadIdx.x & 63) == 0) atomicAdd(&scal[k], s);
    }
}

// O(N^2): grid (n/256, NJ). by==0 blocks also do the center-dependent
// point reductions (old passB).
template<bool PART>
__global__ void passC(const float* __restrict__ pts, const void* hm,
                      float* __restrict__ ws, int n) {
    float* scal = ws;
    const float4* __restrict__ pos4 = (const float4*)(ws + 64);
    const float2* __restrict__ xv2  = (const float2*)(ws + 64 + 4*n);
    float* __restrict__ outb = ws + 64 + 6*n;
    int tid = threadIdx.x;
    int i = blockIdx.x * 256 + tid;
    int by = blockIdx.y;

    if (by == 0) {  // fused passB
        int hInt = (scal[19] == 0.0f);
        float nh = scal[3];
        float inv = (nh > 0.0f) ? 1.0f/nh : 0.0f;
        float cx = scal[0]*inv, cy = scal[1]*inv, cz = scal[2]*inv;
        float x = pts[3*i], y = pts[3*i+1], z = pts[3*i+2];
        int h = read_mask(hm, i, hInt);
        float m = h ? 1.0f : 0.0f;
        float dx = x - cx, dy = y - cy, dz = z - cz;
        float d = sqrtf(dx*dx + dy*dy + dz*dz);
        float vals[8] = { m*dx*dx, m*dx*dy, m*dx*dz, m*dy*dy, m*dy*dz, m*dz*dz,
                          m*d, m*d*d };
        #pragma unroll
        for (int k = 0; k < 8; ++k) {
            float s = wave_sum(vals[k]);
            if ((tid & 63) == 0) atomicAdd(&scal[7 + k], s);
        }
        float dm = wave_max(h ? d : 0.0f);
        if ((tid & 63) == 0) atomicMax((int*)&scal[15], __float_as_int(dm));
    }

    __shared__ float4 t4[256];
    __shared__ float2 tv[256];
    int j = by * 256 + tid;
    t4[tid] = pos4[j];
    tv[tid] = xv2[j];
    __syncthreads();

    float4 pi4 = pos4[i];
    float xi = pi4.x * -0.5f, yi = pi4.y * -0.5f, zi = pi4.z * -0.5f;
    float sqi = pi4.w;
    float ci = 0.f, s1 = 0.f, s2 = 0.f;
    #pragma unroll 8
    for (int k = 0; k < 256; ++k) {
        float4 pj = t4[k];
        float2 vv = tv[k];
        float t = fmaf(pj.x, xi, pj.w);
        t = fmaf(pj.y, yi, t);
        t = fmaf(pj.z, zi, t);
        float d2 = t + sqi;
        float m = (d2 < R2C) ? 1.0f : 0.0f;
        ci += m;
        s1 = fmaf(m, vv.x, s1);
        s2 = fmaf(m, vv.y, s2);
    }
    if (PART) {
        outb[(size_t)by*n + i]          = ci;
        outb[(size_t)(NJ + by)*n + i]   = s1;
        outb[(size_t)(2*NJ + by)*n + i] = s2;
    } else {
        atomicAdd(&outb[i],       ci);
        atomicAdd(&outb[n + i],   s1);
        atomicAdd(&outb[2*n + i], s2);
    }
}

template<bool PART>
__global__ void passD(const void* bm, float* ws, int n) {
    float* scal = ws;
    int i = blockIdx.x * blockDim.x + threadIdx.x;
    if (i >= n) return;
    int bInt = (scal[18] == 0.0f);
    const float* outb = ws + 64 + 6*n;
    float c, s1, s2;
    if (PART) {
        c = 0.f; s1 = 0.f; s2 = 0.f;
        #pragma unroll
        for (int k = 0; k < NJ; ++k) {
            c  += outb[(size_t)k*n + i];
            s1 += outb[(size_t)(NJ + k)*n + i];
            s2 += outb[(size_t)(2*NJ + k)*n + i];
        }
    } else {
        c = outb[i]; s1 = outb[n + i]; s2 = outb[2*n + i];
    }
    int b = read_mask(bm, i, bInt);
    float safe_n = fmaxf(c, 2.0f);
    float var = (s2 - s1*s1/safe_n) / (safe_n - 1.0f);
    bool inc = (c > 1.0f) && b;
    float sv = wave_sum(inc ? var : 0.0f);
    float nv = wave_sum(inc ? 1.0f : 0.0f);
    if ((threadIdx.x & 63) == 0) {
        atomicAdd(&scal[16], sv);
        atomicAdd(&scal[17], nv);
    }
}

__global__ void passE(const float* scal, float* out) {
    float nh = scal[3];
    float el = 0.0f;
    if (nh >= 10.0f) {
        double n  = (double)nh;
        double axx = scal[7]/n,  axy = scal[8]/n,  axz = scal[9]/n;
        double ayy = scal[10]/n, ayz = scal[11]/n, azz = scal[12]/n;
        double p1 = axy*axy + axz*axz + ayz*ayz;
        double q  = (axx + ayy + azz) / 3.0;
        double p2 = (axx-q)*(axx-q) + (ayy-q)*(ayy-q) + (azz-q)*(azz-q) + 2.0*p1;
        double e0, e2;
        if (p2 < 1e-300) { e0 = e2 = q; }
        else {
            double p = sqrt(p2 / 6.0);
            double bxx = (axx-q)/p, byy = (ayy-q)/p, bzz = (azz-q)/p;
            double bxy = axy/p, bxz = axz/p, byz = ayz/p;
            double detB = bxx*(byy*bzz - byz*byz) - bxy*(bxy*bzz - byz*bxz)
                        + bxz*(bxy*byz - byy*bxz);
            double r = fmin(1.0, fmax(-1.0, detB * 0.5));
            double phi = acos(r) / 3.0;
            e2 = q + 2.0*p*cos(phi);                       // largest
            e0 = q + 2.0*p*cos(phi + 2.0943951023931953);  // smallest
        }
        double e1 = 3.0*q - e2 - e0;
        double ra = e1/(e2 + (double)EPSF) - 1.0;
        double rc = e0/(e2 + (double)EPSF) - 1.0;
        el = (float)(ra*ra + rc*rc);
    }
    float pv = scal[4], gv = scal[5];
    float diff = pv - gv;
    float vol = diff * diff;
    float rel = fabsf(diff) / (gv > 0.0f ? gv : 1.0f);
    float sc = (gv > 0.0f) ? vol + 0.5f*rel : vol;
    float nb = scal[6], sv = scal[16], ni = scal[17];
    float mean_var = sv / fmaxf(ni, 1.0f);
    float ss = ((nb >= 5.0f) && (ni > 0.0f)) ? mean_var : 0.0f;
    float conn = 0.0f;
    if (nh >= 5.0f) {
        float sd = scal[13], sd2 = scal[14];
        float var = (sd2 - sd*sd/nh) / (nh - 1.0f);
        conn = var / (scal[15] + EPSF);
    }
    out[0] = el + sc + ss + conn;
}

extern "C" void kernel_launch(void* const* d_in, const int* in_sizes, int n_in,
                              void* d_out, int out_size, void* d_ws, size_t ws_size,
                              hipStream_t stream) {
    const float* points = (const float*)d_in[0];
    const float* segp   = (const float*)d_in[1];
    const void*  bmask  = d_in[2];
    const void*  hmask  = d_in[3];
    const void*  pmask  = d_in[4];
    const void*  gmask  = d_in[5];
    float* ws  = (float*)d_ws;
    float* out = (float*)d_out;
    int n = in_sizes[2];            // 8192
    int nb = n / 256;

    size_t needP = ((size_t)64 + 6*(size_t)n + 3*(size_t)NJ*n) * sizeof(float);
    bool part = ws_size >= needP;

    detect_kernel<<<1, 256, 0, stream>>>(bmask, hmask, pmask, gmask, ws, n);
    passA<<<nb, 256, 0, stream>>>(points, segp, bmask, hmask, pmask, gmask, ws, n);
    if (part) {
        passC<true><<<dim3(nb, NJ), 256, 0, stream>>>(points, hmask, ws, n);
        passD<true><<<nb, 256, 0, stream>>>(bmask, ws, n);
    } else {
        passC<false><<<dim3(nb, NJ), 256, 0, stream>>>(points, hmask, ws, n);
        passD<false><<<nb, 256, 0, stream>>>(bmask, ws, n);
    }
    passE<<<1, 1, 0, stream>>>(ws, out);
}